// Round 1
// baseline (217.925 us; speedup 1.0000x reference)
//
#include <hip/hip_runtime.h>

#define BATCH 4096
#define DIM   512
#define NROW  8192         // 2*BATCH
#define BM    128
#define BN    128
#define BK    64
#define LDT   72           // padded LDS stride (elements): 144B -> 2-way bank conflict only

typedef __attribute__((ext_vector_type(8))) short bf16x8;
typedef __attribute__((ext_vector_type(4))) float f32x4;

__device__ inline unsigned short f2bf(float f) {
    unsigned int u = __float_as_uint(f);
    u += 0x7fffu + ((u >> 16) & 1u);   // round-to-nearest-even
    return (unsigned short)(u >> 16);
}

// ---------------- Kernel 1: normalize rows + positives ----------------
// grid = BATCH blocks, 64 threads (1 wave). Row i of emb_i -> reps[i],
// row i of emb_j -> reps[BATCH+i], pos[i] = <z_i, z_j>.
__global__ __launch_bounds__(64) void normalize_pos_kernel(
    const float* __restrict__ ei, const float* __restrict__ ej,
    unsigned short* __restrict__ reps, float* __restrict__ pos) {
    const int i = blockIdx.x;
    const int t = threadIdx.x;            // 0..63

    const float4* ri = (const float4*)(ei + (size_t)i * DIM);
    const float4* rj = (const float4*)(ej + (size_t)i * DIM);
    float4 a0 = ri[t], a1 = ri[t + 64];
    float4 b0 = rj[t], b1 = rj[t + 64];

    float si  = a0.x*a0.x + a0.y*a0.y + a0.z*a0.z + a0.w*a0.w
              + a1.x*a1.x + a1.y*a1.y + a1.z*a1.z + a1.w*a1.w;
    float sj  = b0.x*b0.x + b0.y*b0.y + b0.z*b0.z + b0.w*b0.w
              + b1.x*b1.x + b1.y*b1.y + b1.z*b1.z + b1.w*b1.w;
    float dij = a0.x*b0.x + a0.y*b0.y + a0.z*b0.z + a0.w*b0.w
              + a1.x*b1.x + a1.y*b1.y + a1.z*b1.z + a1.w*b1.w;

    #pragma unroll
    for (int m = 1; m < 64; m <<= 1) {
        si  += __shfl_xor(si,  m);
        sj  += __shfl_xor(sj,  m);
        dij += __shfl_xor(dij, m);
    }

    float invi = 1.0f / fmaxf(sqrtf(si), 1e-12f);
    float invj = 1.0f / fmaxf(sqrtf(sj), 1e-12f);

    ushort4 o0, o1, p0, p1;
    o0.x = f2bf(a0.x*invi); o0.y = f2bf(a0.y*invi); o0.z = f2bf(a0.z*invi); o0.w = f2bf(a0.w*invi);
    o1.x = f2bf(a1.x*invi); o1.y = f2bf(a1.y*invi); o1.z = f2bf(a1.z*invi); o1.w = f2bf(a1.w*invi);
    p0.x = f2bf(b0.x*invj); p0.y = f2bf(b0.y*invj); p0.z = f2bf(b0.z*invj); p0.w = f2bf(b0.w*invj);
    p1.x = f2bf(b1.x*invj); p1.y = f2bf(b1.y*invj); p1.z = f2bf(b1.z*invj); p1.w = f2bf(b1.w*invj);

    ushort4* wi = (ushort4*)(reps + (size_t)i * DIM);
    ushort4* wj = (ushort4*)(reps + (size_t)(BATCH + i) * DIM);
    wi[t] = o0; wi[t + 64] = o1;
    wj[t] = p0; wj[t + 64] = p1;

    if (t == 0) pos[i] = dij * invi * invj;
}

// ---------------- Kernel 2: fused sim GEMM + exp row-sums ----------------
// grid = (NROW/BN, NROW/BM), 256 threads (4 waves, 2x2).
// Block (bx, by): rows [by*BM, +BM) x cols [bx*BN, +BN).
// partials[bx][row] = sum_{c in col tile, c != row} exp(sim[row][c]/TEMP)
__global__ __launch_bounds__(256) void simsum_kernel(
    const unsigned short* __restrict__ reps,
    float* __restrict__ partials) {
    __shared__ unsigned short As[BM * LDT];
    __shared__ unsigned short Bs[BN * LDT];
    __shared__ float rowsum[2][BM];

    const int tid  = threadIdx.x;
    const int lane = tid & 63;
    const int wave = tid >> 6;
    const int wr = wave >> 1, wc = wave & 1;
    const int rowBase = blockIdx.y * BM;
    const int colBase = blockIdx.x * BN;

    f32x4 acc[4][4];
    #pragma unroll
    for (int m = 0; m < 4; ++m)
        #pragma unroll
        for (int n = 0; n < 4; ++n)
            acc[m][n] = (f32x4){0.f, 0.f, 0.f, 0.f};

    for (int kb = 0; kb < DIM; kb += BK) {
        __syncthreads();
        // stage 128x64 bf16 A and B tiles; 256 threads x 4 chunks x 16B
        #pragma unroll
        for (int i = 0; i < 4; ++i) {
            int c   = tid + i * 256;      // 0..1023
            int row = c >> 3;             // 0..127
            int k8  = (c & 7) << 3;       // 0,8,..,56
            *(bf16x8*)&As[row * LDT + k8] =
                *(const bf16x8*)&reps[(size_t)(rowBase + row) * DIM + kb + k8];
            *(bf16x8*)&Bs[row * LDT + k8] =
                *(const bf16x8*)&reps[(size_t)(colBase + row) * DIM + kb + k8];
        }
        __syncthreads();

        #pragma unroll
        for (int kk = 0; kk < 2; ++kk) {
            const int ko = kk * 32 + ((lane >> 4) << 3);
            bf16x8 af[4], bfr[4];
            #pragma unroll
            for (int m = 0; m < 4; ++m)
                af[m] = *(const bf16x8*)&As[(wr * 64 + m * 16 + (lane & 15)) * LDT + ko];
            #pragma unroll
            for (int n = 0; n < 4; ++n)
                bfr[n] = *(const bf16x8*)&Bs[(wc * 64 + n * 16 + (lane & 15)) * LDT + ko];
            #pragma unroll
            for (int m = 0; m < 4; ++m)
                #pragma unroll
                for (int n = 0; n < 4; ++n)
                    acc[m][n] = __builtin_amdgcn_mfma_f32_16x16x32_bf16(
                        af[m], bfr[n], acc[m][n], 0, 0, 0);
        }
    }

    // epilogue: exp(sim/TEMP) with diagonal masked, reduce to per-row sums
    const float SCALE = 2.8853900817779268f;   // 1/(TEMP*ln2) = 2/ln2
    #pragma unroll
    for (int m = 0; m < 4; ++m) {
        const int lrow0 = wr * 64 + m * 16 + ((lane >> 4) << 2);
        const int grow0 = rowBase + lrow0;
        float rs[4] = {0.f, 0.f, 0.f, 0.f};
        #pragma unroll
        for (int n = 0; n < 4; ++n) {
            const int gcol = colBase + wc * 64 + n * 16 + (lane & 15);
            #pragma unroll
            for (int j = 0; j < 4; ++j) {
                float e = exp2f(acc[m][n][j] * SCALE);
                if (grow0 + j == gcol) e = 0.f;   // exclude diagonal
                rs[j] += e;
            }
        }
        #pragma unroll
        for (int j = 0; j < 4; ++j) {
            float v = rs[j];
            v += __shfl_xor(v, 1);
            v += __shfl_xor(v, 2);
            v += __shfl_xor(v, 4);
            v += __shfl_xor(v, 8);
            if ((lane & 15) == 0)
                rowsum[wc][lrow0 + j] = v;
        }
    }
    __syncthreads();
    if (tid < BM)
        partials[(size_t)blockIdx.x * NROW + rowBase + tid] =
            rowsum[0][tid] + rowsum[1][tid];
}

// ---------------- Kernel 3: finalize ----------------
__global__ __launch_bounds__(256) void finalize_kernel(
    const float* __restrict__ partials, const float* __restrict__ pos,
    float* __restrict__ out) {
    const int t = threadIdx.x;
    double s = 0.0;
    for (int r = t; r < NROW; r += 256) {
        float denom = 0.f;
        #pragma unroll 8
        for (int c = 0; c < NROW / BN; ++c)
            denom += partials[(size_t)c * NROW + r];
        float p = pos[r & (BATCH - 1)];
        s += (double)(logf(denom) - p * 2.0f);   // /TEMP == *2
    }
    __shared__ double red[256];
    red[t] = s;
    __syncthreads();
    for (int off = 128; off > 0; off >>= 1) {
        if (t < off) red[t] += red[t + off];
        __syncthreads();
    }
    if (t == 0) out[0] = (float)(red[0] / (double)NROW);
}

extern "C" void kernel_launch(void* const* d_in, const int* in_sizes, int n_in,
                              void* d_out, int out_size, void* d_ws, size_t ws_size,
                              hipStream_t stream) {
    const float* ei = (const float*)d_in[0];
    const float* ej = (const float*)d_in[1];
    float* out = (float*)d_out;

    // workspace layout: reps bf16 [8192][512] (8 MB) | pos f32 [4096] | partials f32 [64][8192] (2 MB)
    unsigned short* reps = (unsigned short*)d_ws;
    float* pos      = (float*)((char*)d_ws + (size_t)NROW * DIM * 2);
    float* partials = pos + BATCH;

    normalize_pos_kernel<<<BATCH, 64, 0, stream>>>(ei, ej, reps, pos);
    dim3 grid(NROW / BN, NROW / BM);
    simsum_kernel<<<grid, 256, 0, stream>>>(reps, partials);
    finalize_kernel<<<1, 256, 0, stream>>>(partials, pos, out);
}

// Round 2
// 98.757 us; speedup vs baseline: 2.2067x; 2.2067x over previous
//
#include <hip/hip_runtime.h>

#define BATCH 4096
#define DIM   512
#define NROW  8192         // 2*BATCH
#define BM    128
#define BN    128
#define BK    64
#define NC    (NROW / BN)  // 64 column/row chunks

typedef __attribute__((ext_vector_type(8))) short bf16x8;
typedef __attribute__((ext_vector_type(4))) float f32x4;

__device__ inline unsigned short f2bf(float f) {
    unsigned int u = __float_as_uint(f);
    u += 0x7fffu + ((u >> 16) & 1u);   // round-to-nearest-even
    return (unsigned short)(u >> 16);
}

__device__ inline void gload_lds16(const unsigned short* g, unsigned short* l) {
    __builtin_amdgcn_global_load_lds(
        (const __attribute__((address_space(1))) void*)g,
        (__attribute__((address_space(3))) void*)l, 16, 0, 0);
}

// ---------------- Kernel 1: normalize rows + positives ----------------
__global__ __launch_bounds__(64) void normalize_pos_kernel(
    const float* __restrict__ ei, const float* __restrict__ ej,
    unsigned short* __restrict__ reps, float* __restrict__ pos) {
    const int i = blockIdx.x;
    const int t = threadIdx.x;            // 0..63

    const float4* ri = (const float4*)(ei + (size_t)i * DIM);
    const float4* rj = (const float4*)(ej + (size_t)i * DIM);
    float4 a0 = ri[t], a1 = ri[t + 64];
    float4 b0 = rj[t], b1 = rj[t + 64];

    float si  = a0.x*a0.x + a0.y*a0.y + a0.z*a0.z + a0.w*a0.w
              + a1.x*a1.x + a1.y*a1.y + a1.z*a1.z + a1.w*a1.w;
    float sj  = b0.x*b0.x + b0.y*b0.y + b0.z*b0.z + b0.w*b0.w
              + b1.x*b1.x + b1.y*b1.y + b1.z*b1.z + b1.w*b1.w;
    float dij = a0.x*b0.x + a0.y*b0.y + a0.z*b0.z + a0.w*b0.w
              + a1.x*b1.x + a1.y*b1.y + a1.z*b1.z + a1.w*b1.w;

    #pragma unroll
    for (int m = 1; m < 64; m <<= 1) {
        si  += __shfl_xor(si,  m);
        sj  += __shfl_xor(sj,  m);
        dij += __shfl_xor(dij, m);
    }

    float invi = 1.0f / fmaxf(sqrtf(si), 1e-12f);
    float invj = 1.0f / fmaxf(sqrtf(sj), 1e-12f);

    ushort4 o0, o1, p0, p1;
    o0.x = f2bf(a0.x*invi); o0.y = f2bf(a0.y*invi); o0.z = f2bf(a0.z*invi); o0.w = f2bf(a0.w*invi);
    o1.x = f2bf(a1.x*invi); o1.y = f2bf(a1.y*invi); o1.z = f2bf(a1.z*invi); o1.w = f2bf(a1.w*invi);
    p0.x = f2bf(b0.x*invj); p0.y = f2bf(b0.y*invj); p0.z = f2bf(b0.z*invj); p0.w = f2bf(b0.w*invj);
    p1.x = f2bf(b1.x*invj); p1.y = f2bf(b1.y*invj); p1.z = f2bf(b1.z*invj); p1.w = f2bf(b1.w*invj);

    ushort4* wi = (ushort4*)(reps + (size_t)i * DIM);
    ushort4* wj = (ushort4*)(reps + (size_t)(BATCH + i) * DIM);
    wi[t] = o0; wi[t + 64] = o1;
    wj[t] = p0; wj[t + 64] = p1;

    if (t == 0) pos[i] = dij * invi * invj;
}

// ---------------- Kernel 2: triangle-fused sim GEMM + exp row/col sums ----
// grid = NC*(NC+1)/2 blocks (upper triangle rc <= cc), 256 threads (4 waves).
// partials[c][r] = sum over cols in chunk c (excl diag) of exp(sim[r][col]/T)
//   row-sums of block (rc,cc) -> partials[cc][rows in rc]
//   col-sums of block (rc,cc) -> partials[rc][rows in cc]   (symmetry, rc<cc)
__global__ __launch_bounds__(256) void simsum_kernel(
    const unsigned short* __restrict__ reps,
    float* __restrict__ partials) {
    __shared__ unsigned short As[BM * BK];   // linear: row stride 64 elems
    __shared__ unsigned short Bs[BN * BK];
    __shared__ float rowsumLDS[2][BM];       // [wc][local row]
    __shared__ float colsumLDS[2][BN];       // [wr][local col]

    // decode triangle block index -> (rc, cc), rc <= cc
    int b = blockIdx.x;
    int rc = 0;
    while (b >= NC - rc) { b -= NC - rc; ++rc; }
    const int cc = rc + b;

    const int tid  = threadIdx.x;
    const int lane = tid & 63;
    const int wave = tid >> 6;
    const int wr = wave >> 1, wc = wave & 1;
    const int rowBase = rc * BM;
    const int colBase = cc * BN;

    f32x4 acc[4][4];
    #pragma unroll
    for (int m = 0; m < 4; ++m)
        #pragma unroll
        for (int n = 0; n < 4; ++n)
            acc[m][n] = (f32x4){0.f, 0.f, 0.f, 0.f};

    const unsigned short* gA = reps + (size_t)rowBase * DIM;
    const unsigned short* gB = reps + (size_t)colBase * DIM;
    const int lrow = lane >> 3;            // 0..7 within 8-row chunk
    const int lk   = (lane & 7) << 3;      // element offset 0..56

    for (int kb = 0; kb < DIM; kb += BK) {
        __syncthreads();   // previous compute done before overwrite
        // stage: each wave DMA's 4 chunks of 8 rows for A and B
        #pragma unroll
        for (int i = 0; i < 4; ++i) {
            const int r0 = wave * 32 + i * 8;
            gload_lds16(gA + (size_t)(r0 + lrow) * DIM + kb + lk, &As[r0 * BK]);
            gload_lds16(gB + (size_t)(r0 + lrow) * DIM + kb + lk, &Bs[r0 * BK]);
        }
        __syncthreads();   // vmcnt(0) drained by barrier semantics

        #pragma unroll
        for (int kk = 0; kk < 2; ++kk) {
            const int ko = kk * 32 + ((lane >> 4) << 3);
            bf16x8 af[4], bfr[4];
            #pragma unroll
            for (int m = 0; m < 4; ++m)
                af[m] = *(const bf16x8*)&As[(wr * 64 + m * 16 + (lane & 15)) * BK + ko];
            #pragma unroll
            for (int n = 0; n < 4; ++n)
                bfr[n] = *(const bf16x8*)&Bs[(wc * 64 + n * 16 + (lane & 15)) * BK + ko];
            #pragma unroll
            for (int m = 0; m < 4; ++m)
                #pragma unroll
                for (int n = 0; n < 4; ++n)
                    acc[m][n] = __builtin_amdgcn_mfma_f32_16x16x32_bf16(
                        af[m], bfr[n], acc[m][n], 0, 0, 0);
        }
    }

    // epilogue: e = exp(sim/TEMP), diag masked; produce row sums AND col sums
    const float SCALE = 2.8853900817779268f;   // 1/(TEMP*ln2) = 2/ln2
    float colacc[4] = {0.f, 0.f, 0.f, 0.f};
    #pragma unroll
    for (int m = 0; m < 4; ++m) {
        const int lrow0 = wr * 64 + m * 16 + ((lane >> 4) << 2);
        const int grow0 = rowBase + lrow0;
        float rs[4] = {0.f, 0.f, 0.f, 0.f};
        #pragma unroll
        for (int n = 0; n < 4; ++n) {
            const int gcol = colBase + wc * 64 + n * 16 + (lane & 15);
            #pragma unroll
            for (int j = 0; j < 4; ++j) {
                float e = exp2f(acc[m][n][j] * SCALE);
                if (grow0 + j == gcol) e = 0.f;   // exclude self-similarity
                rs[j] += e;
                colacc[n] += e;
            }
        }
        #pragma unroll
        for (int j = 0; j < 4; ++j) {
            float v = rs[j];
            v += __shfl_xor(v, 1);
            v += __shfl_xor(v, 2);
            v += __shfl_xor(v, 4);
            v += __shfl_xor(v, 8);
            if ((lane & 15) == 0)
                rowsumLDS[wc][lrow0 + j] = v;
        }
    }
    #pragma unroll
    for (int n = 0; n < 4; ++n) {
        float v = colacc[n];
        v += __shfl_xor(v, 16);
        v += __shfl_xor(v, 32);
        if (lane < 16)
            colsumLDS[wr][wc * 64 + n * 16 + lane] = v;
    }
    __syncthreads();
    if (tid < BM) {
        partials[(size_t)cc * NROW + rowBase + tid] =
            rowsumLDS[0][tid] + rowsumLDS[1][tid];
        if (rc != cc)
            partials[(size_t)rc * NROW + colBase + tid] =
                colsumLDS[0][tid] + colsumLDS[1][tid];
    }
}

// ---------------- Kernel 3a: per-row loss, per-block partial sums --------
__global__ __launch_bounds__(256) void rowloss_kernel(
    const float* __restrict__ partials, const float* __restrict__ pos,
    double* __restrict__ blocksum) {
    const int t = threadIdx.x;
    const int r = blockIdx.x * 256 + t;
    float denom = 0.f;
    #pragma unroll 8
    for (int c = 0; c < NC; ++c)
        denom += partials[(size_t)c * NROW + r];
    double v = (double)(logf(denom) - 2.0f * pos[r & (BATCH - 1)]);  // /TEMP == *2
    __shared__ double red[256];
    red[t] = v;
    __syncthreads();
    for (int off = 128; off > 0; off >>= 1) {
        if (t < off) red[t] += red[t + off];
        __syncthreads();
    }
    if (t == 0) blocksum[blockIdx.x] = red[0];
}

// ---------------- Kernel 3b: final scalar --------------------------------
__global__ void final2_kernel(const double* __restrict__ blocksum,
                              float* __restrict__ out) {
    if (threadIdx.x == 0) {
        double s = 0.0;
        #pragma unroll
        for (int i = 0; i < NROW / 256; ++i) s += blocksum[i];
        out[0] = (float)(s / (double)NROW);
    }
}

extern "C" void kernel_launch(void* const* d_in, const int* in_sizes, int n_in,
                              void* d_out, int out_size, void* d_ws, size_t ws_size,
                              hipStream_t stream) {
    const float* ei = (const float*)d_in[0];
    const float* ej = (const float*)d_in[1];
    float* out = (float*)d_out;

    // ws layout: reps bf16 [8192][512] (8 MB) | pos f32 [4096] |
    //            partials f32 [64][8192] (2 MB) | blocksum f64 [32]
    unsigned short* reps = (unsigned short*)d_ws;
    float* pos      = (float*)((char*)d_ws + (size_t)NROW * DIM * 2);
    float* partials = pos + BATCH;
    double* blocksum = (double*)(partials + (size_t)NC * NROW);

    normalize_pos_kernel<<<BATCH, 64, 0, stream>>>(ei, ej, reps, pos);
    simsum_kernel<<<NC * (NC + 1) / 2, 256, 0, stream>>>(reps, partials);
    rowloss_kernel<<<NROW / 256, 256, 0, stream>>>(partials, pos, blocksum);
    final2_kernel<<<1, 64, 0, stream>>>(blocksum, out);
}

// Round 3
// 91.508 us; speedup vs baseline: 2.3815x; 1.0792x over previous
//
#include <hip/hip_runtime.h>

#define BATCH 4096
#define DIM   512
#define NROW  8192                    // 2*BATCH
#define BT    256                     // square tile
#define BK    32                      // K-step
#define NCH   (NROW / BT)             // 32 chunks
#define NBLK  (NCH * (NCH + 1) / 2)   // 528 triangle blocks
#define NT    (DIM / BK)              // 16 K-tiles

typedef __attribute__((ext_vector_type(8))) short bf16x8;
typedef __attribute__((ext_vector_type(4))) float f32x4;

__device__ inline unsigned short f2bf(float f) {
    unsigned int u = __float_as_uint(f);
    u += 0x7fffu + ((u >> 16) & 1u);   // round-to-nearest-even
    return (unsigned short)(u >> 16);
}

// DMA one 16-row x 64B chunk into LDS. LDS dest is linear (wave-uniform base +
// lane*16); the XOR swizzle lives in the per-lane GLOBAL source address:
// LDS(row, slot') holds global(row, slot' ^ ((row>>1)&3)).
__device__ __forceinline__ void stage16(const unsigned short* __restrict__ grow,
                                        unsigned short* lds_chunk, int lane) {
    const int r  = lane >> 2;                          // row within chunk 0..15
    const int gs = (lane & 3) ^ ((lane >> 3) & 3);     // swizzled 16B slot
    const char* g = (const char*)(grow + (size_t)r * DIM) + gs * 16;
    __builtin_amdgcn_global_load_lds(
        (const __attribute__((address_space(1))) void*)g,
        (__attribute__((address_space(3))) void*)lds_chunk, 16, 0, 0);
}

// ---------------- Kernel 1: normalize rows + positives ----------------
__global__ __launch_bounds__(64) void normalize_pos_kernel(
    const float* __restrict__ ei, const float* __restrict__ ej,
    unsigned short* __restrict__ reps, float* __restrict__ pos) {
    const int i = blockIdx.x;
    const int t = threadIdx.x;            // 0..63

    const float4* ri = (const float4*)(ei + (size_t)i * DIM);
    const float4* rj = (const float4*)(ej + (size_t)i * DIM);
    float4 a0 = ri[t], a1 = ri[t + 64];
    float4 b0 = rj[t], b1 = rj[t + 64];

    float si  = a0.x*a0.x + a0.y*a0.y + a0.z*a0.z + a0.w*a0.w
              + a1.x*a1.x + a1.y*a1.y + a1.z*a1.z + a1.w*a1.w;
    float sj  = b0.x*b0.x + b0.y*b0.y + b0.z*b0.z + b0.w*b0.w
              + b1.x*b1.x + b1.y*b1.y + b1.z*b1.z + b1.w*b1.w;
    float dij = a0.x*b0.x + a0.y*b0.y + a0.z*b0.z + a0.w*b0.w
              + a1.x*b1.x + a1.y*b1.y + a1.z*b1.z + a1.w*b1.w;

    #pragma unroll
    for (int m = 1; m < 64; m <<= 1) {
        si  += __shfl_xor(si,  m);
        sj  += __shfl_xor(sj,  m);
        dij += __shfl_xor(dij, m);
    }

    float invi = 1.0f / fmaxf(sqrtf(si), 1e-12f);
    float invj = 1.0f / fmaxf(sqrtf(sj), 1e-12f);

    ushort4 o0, o1, p0, p1;
    o0.x = f2bf(a0.x*invi); o0.y = f2bf(a0.y*invi); o0.z = f2bf(a0.z*invi); o0.w = f2bf(a0.w*invi);
    o1.x = f2bf(a1.x*invi); o1.y = f2bf(a1.y*invi); o1.z = f2bf(a1.z*invi); o1.w = f2bf(a1.w*invi);
    p0.x = f2bf(b0.x*invj); p0.y = f2bf(b0.y*invj); p0.z = f2bf(b0.z*invj); p0.w = f2bf(b0.w*invj);
    p1.x = f2bf(b1.x*invj); p1.y = f2bf(b1.y*invj); p1.z = f2bf(b1.z*invj); p1.w = f2bf(b1.w*invj);

    ushort4* wi = (ushort4*)(reps + (size_t)i * DIM);
    ushort4* wj = (ushort4*)(reps + (size_t)(BATCH + i) * DIM);
    wi[t] = o0; wi[t + 64] = o1;
    wj[t] = p0; wj[t + 64] = p1;

    if (t == 0) pos[i] = dij * invi * invj;
}

// ---------------- Kernel 2: triangle-fused sim GEMM + exp row/col sums ----
// 256x256 tile, 8 waves (2Mx4N), BK=32, 2 LDS slots, 2 phases per K-tile,
// counted vmcnt(2), raw s_barrier, both-sides LDS swizzle, setprio on MFMA.
__global__ __launch_bounds__(512, 2) void simsum_kernel(
    const unsigned short* __restrict__ reps,
    float* __restrict__ partials) {
    __shared__ unsigned short As[2][BT * BK];   // 2 x 16 KB
    __shared__ unsigned short Bs[2][BT * BK];   // 2 x 16 KB
    __shared__ float rowsumLDS[4][BT];
    __shared__ float colsumLDS[2][BT];

    // XCD-aware swizzle (528 % 8 == 0 -> bijective), then triangle decode
    int bid = (blockIdx.x & 7) * (NBLK / 8) + (blockIdx.x >> 3);
    int rc = 0, b = bid;
    while (b >= NCH - rc) { b -= NCH - rc; ++rc; }
    const int cc = rc + b;                      // rc <= cc

    const int tid  = threadIdx.x;
    const int lane = tid & 63;
    const int wave = tid >> 6;                  // 0..7
    const int wr   = wave >> 2;                 // 0..1  (M half)
    const int wc   = wave & 3;                  // 0..3  (N quarter)
    const int s    = lane & 15;
    const int q    = lane >> 4;
    const int rowBase = rc * BT;
    const int colBase = cc * BT;

    const unsigned short* gA = reps + (size_t)rowBase * DIM;
    const unsigned short* gB = reps + (size_t)colBase * DIM;

    // swizzled ds_read byte offsets (XOR term depends only on (s,q))
    const int koS  = ((q ^ ((s >> 1) & 3)) << 4);
    const int aoff = (wr * 128 + s) * 64 + koS;   // + m*1024 per fragment
    const int boff = (wc * 64  + s) * 64 + koS;   // + n*1024 per fragment

    f32x4 acc[8][4];
    #pragma unroll
    for (int m = 0; m < 8; ++m)
        #pragma unroll
        for (int n = 0; n < 4; ++n)
            acc[m][n] = (f32x4){0.f, 0.f, 0.f, 0.f};

    // prologue: stage tile 0 into slot 0 (4 loads/wave)
    stage16(gA + (size_t)(wave * 16) * DIM,       &As[0][wave * 512],       lane);
    stage16(gA + (size_t)((wave + 8) * 16) * DIM, &As[0][(wave + 8) * 512], lane);
    stage16(gB + (size_t)(wave * 16) * DIM,       &Bs[0][wave * 512],       lane);
    stage16(gB + (size_t)((wave + 8) * 16) * DIM, &Bs[0][(wave + 8) * 512], lane);

    bf16x8 af[4], bfr[4];

    for (int t = 0; t < NT - 1; ++t) {
        const int sl = t & 1, sn = sl ^ 1;
        const char* Asl = (const char*)As[sl];
        const char* Bsl = (const char*)Bs[sl];
        const int kb = (t + 1) * BK;

        // ---------------- phase A ----------------
        stage16(gA + (size_t)(wave * 16) * DIM + kb,       &As[sn][wave * 512],       lane);
        stage16(gA + (size_t)((wave + 8) * 16) * DIM + kb, &As[sn][(wave + 8) * 512], lane);
        asm volatile("s_waitcnt vmcnt(2)" ::: "memory");   // tile t fully landed
        __builtin_amdgcn_sched_barrier(0);
        __builtin_amdgcn_s_barrier();
        __builtin_amdgcn_sched_barrier(0);
        #pragma unroll
        for (int m = 0; m < 4; ++m)
            af[m] = *(const bf16x8*)(Asl + aoff + m * 1024);
        #pragma unroll
        for (int n = 0; n < 4; ++n)
            bfr[n] = *(const bf16x8*)(Bsl + boff + n * 1024);
        asm volatile("s_waitcnt lgkmcnt(0)" ::: "memory");
        __builtin_amdgcn_sched_barrier(0);
        __builtin_amdgcn_s_setprio(1);
        #pragma unroll
        for (int m = 0; m < 4; ++m)
            #pragma unroll
            for (int n = 0; n < 4; ++n)
                acc[m][n] = __builtin_amdgcn_mfma_f32_16x16x32_bf16(
                    af[m], bfr[n], acc[m][n], 0, 0, 0);
        __builtin_amdgcn_s_setprio(0);
        __builtin_amdgcn_s_barrier();

        // ---------------- phase B ----------------
        #pragma unroll
        for (int m = 0; m < 4; ++m)
            af[m] = *(const bf16x8*)(Asl + aoff + (4 + m) * 1024);
        stage16(gB + (size_t)(wave * 16) * DIM + kb,       &Bs[sn][wave * 512],       lane);
        stage16(gB + (size_t)((wave + 8) * 16) * DIM + kb, &Bs[sn][(wave + 8) * 512], lane);
        __builtin_amdgcn_s_barrier();
        asm volatile("s_waitcnt lgkmcnt(0)" ::: "memory");
        __builtin_amdgcn_sched_barrier(0);
        __builtin_amdgcn_s_setprio(1);
        #pragma unroll
        for (int m = 0; m < 4; ++m)
            #pragma unroll
            for (int n = 0; n < 4; ++n)
                acc[4 + m][n] = __builtin_amdgcn_mfma_f32_16x16x32_bf16(
                    af[m], bfr[n], acc[4 + m][n], 0, 0, 0);
        __builtin_amdgcn_s_setprio(0);
        __builtin_amdgcn_s_barrier();
    }

    // -------- peeled last K-tile (t = NT-1, slot 1): drain, no stages ------
    {
        const char* Asl = (const char*)As[1];
        const char* Bsl = (const char*)Bs[1];
        asm volatile("s_waitcnt vmcnt(0)" ::: "memory");
        __builtin_amdgcn_sched_barrier(0);
        __builtin_amdgcn_s_barrier();
        __builtin_amdgcn_sched_barrier(0);
        #pragma unroll
        for (int m = 0; m < 4; ++m)
            af[m] = *(const bf16x8*)(Asl + aoff + m * 1024);
        #pragma unroll
        for (int n = 0; n < 4; ++n)
            bfr[n] = *(const bf16x8*)(Bsl + boff + n * 1024);
        asm volatile("s_waitcnt lgkmcnt(0)" ::: "memory");
        __builtin_amdgcn_sched_barrier(0);
        __builtin_amdgcn_s_setprio(1);
        #pragma unroll
        for (int m = 0; m < 4; ++m)
            #pragma unroll
            for (int n = 0; n < 4; ++n)
                acc[m][n] = __builtin_amdgcn_mfma_f32_16x16x32_bf16(
                    af[m], bfr[n], acc[m][n], 0, 0, 0);
        __builtin_amdgcn_s_setprio(0);
        #pragma unroll
        for (int m = 0; m < 4; ++m)
            af[m] = *(const bf16x8*)(Asl + aoff + (4 + m) * 1024);
        asm volatile("s_waitcnt lgkmcnt(0)" ::: "memory");
        __builtin_amdgcn_sched_barrier(0);
        __builtin_amdgcn_s_setprio(1);
        #pragma unroll
        for (int m = 0; m < 4; ++m)
            #pragma unroll
            for (int n = 0; n < 4; ++n)
                acc[4 + m][n] = __builtin_amdgcn_mfma_f32_16x16x32_bf16(
                    af[m], bfr[n], acc[4 + m][n], 0, 0, 0);
        __builtin_amdgcn_s_setprio(0);
    }

    // -------- epilogue: exp(sim/T), diag masked; row sums AND col sums -----
    const float SCALE = 2.8853900817779268f;   // 1/(TEMP*ln2) = 2/ln2
    float colacc[4] = {0.f, 0.f, 0.f, 0.f};
    #pragma unroll
    for (int m = 0; m < 8; ++m) {
        const int lrow0 = wr * 128 + m * 16 + (q << 2);
        const int grow0 = rowBase + lrow0;
        float rs[4] = {0.f, 0.f, 0.f, 0.f};
        #pragma unroll
        for (int n = 0; n < 4; ++n) {
            const int gcol = colBase + wc * 64 + n * 16 + s;
            #pragma unroll
            for (int j = 0; j < 4; ++j) {
                float e = exp2f(acc[m][n][j] * SCALE);
                if (grow0 + j == gcol) e = 0.f;   // exclude self-similarity
                rs[j] += e;
                colacc[n] += e;
            }
        }
        #pragma unroll
        for (int j = 0; j < 4; ++j) {
            float v = rs[j];
            v += __shfl_xor(v, 1);
            v += __shfl_xor(v, 2);
            v += __shfl_xor(v, 4);
            v += __shfl_xor(v, 8);
            if (s == 0) rowsumLDS[wc][lrow0 + j] = v;
        }
    }
    #pragma unroll
    for (int n = 0; n < 4; ++n) {
        float v = colacc[n];
        v += __shfl_xor(v, 16);
        v += __shfl_xor(v, 32);
        if (q == 0) colsumLDS[wr][wc * 64 + n * 16 + s] = v;
    }
    __syncthreads();
    if (tid < BT) {
        partials[(size_t)cc * NROW + rowBase + tid] =
            rowsumLDS[0][tid] + rowsumLDS[1][tid] +
            rowsumLDS[2][tid] + rowsumLDS[3][tid];
        if (rc != cc)
            partials[(size_t)rc * NROW + colBase + tid] =
                colsumLDS[0][tid] + colsumLDS[1][tid];
    }
}

// ---------------- Kernel 3a: per-row loss, per-block partial sums --------
__global__ __launch_bounds__(256) void rowloss_kernel(
    const float* __restrict__ partials, const float* __restrict__ pos,
    double* __restrict__ blocksum) {
    const int t = threadIdx.x;
    const int r = blockIdx.x * 256 + t;
    float denom = 0.f;
    #pragma unroll 8
    for (int c = 0; c < NCH; ++c)
        denom += partials[(size_t)c * NROW + r];
    double v = (double)(logf(denom) - 2.0f * pos[r & (BATCH - 1)]);  // /TEMP == *2
    __shared__ double red[256];
    red[t] = v;
    __syncthreads();
    for (int off = 128; off > 0; off >>= 1) {
        if (t < off) red[t] += red[t + off];
        __syncthreads();
    }
    if (t == 0) blocksum[blockIdx.x] = red[0];
}

// ---------------- Kernel 3b: final scalar --------------------------------
__global__ void final2_kernel(const double* __restrict__ blocksum,
                              float* __restrict__ out) {
    if (threadIdx.x == 0) {
        double ssum = 0.0;
        #pragma unroll
        for (int i = 0; i < NROW / 256; ++i) ssum += blocksum[i];
        out[0] = (float)(ssum / (double)NROW);
    }
}

extern "C" void kernel_launch(void* const* d_in, const int* in_sizes, int n_in,
                              void* d_out, int out_size, void* d_ws, size_t ws_size,
                              hipStream_t stream) {
    const float* ei = (const float*)d_in[0];
    const float* ej = (const float*)d_in[1];
    float* out = (float*)d_out;

    // ws layout: reps bf16 [8192][512] (8 MB) | pos f32 [4096] |
    //            partials f32 [32][8192] (1 MB) | blocksum f64 [32]
    unsigned short* reps = (unsigned short*)d_ws;
    float* pos      = (float*)((char*)d_ws + (size_t)NROW * DIM * 2);
    float* partials = pos + BATCH;
    double* blocksum = (double*)(partials + (size_t)NCH * NROW);

    normalize_pos_kernel<<<BATCH, 64, 0, stream>>>(ei, ej, reps, pos);
    simsum_kernel<<<NBLK, 512, 0, stream>>>(reps, partials);
    rowloss_kernel<<<NROW / 256, 256, 0, stream>>>(partials, pos, blocksum);
    final2_kernel<<<1, 64, 0, stream>>>(blocksum, out);
}

// Round 4
// 79.281 us; speedup vs baseline: 2.7488x; 1.1542x over previous
//
#include <hip/hip_runtime.h>

#define BATCH 4096
#define DIM   512
#define NROW  8192
#define TILE  256
#define QT    128
#define BK    64
#define NCH   32                  // 256-row/col chunks
#define NFULL 496                 // off-diagonal full cells (rc<cc)
#define NQ    96                  // 32 diag cells x 3 quarter-subs
#define NSLOT 33
#define NT    (DIM / BK)          // 8 K-tiles

typedef __attribute__((ext_vector_type(8))) short bf16x8;
typedef __attribute__((ext_vector_type(4))) float f32x4;

__device__ inline unsigned short f2bf(float f) {
    unsigned int u = __float_as_uint(f);
    u += 0x7fffu + ((u >> 16) & 1u);
    return (unsigned short)(u >> 16);
}

__device__ __forceinline__ void gload16(const unsigned short* g, unsigned short* l) {
    __builtin_amdgcn_global_load_lds(
        (const __attribute__((address_space(1))) void*)g,
        (__attribute__((address_space(3))) void*)l, 16, 0, 0);
}

// ---------------- Kernel 1: normalize rows + positives ----------------
__global__ __launch_bounds__(256) void normalize_pos_kernel(
    const float* __restrict__ ei, const float* __restrict__ ej,
    unsigned short* __restrict__ reps, float* __restrict__ pos) {
    const int t = threadIdx.x & 63;
    const int i = blockIdx.x * 4 + (threadIdx.x >> 6);

    const float4* ri = (const float4*)(ei + (size_t)i * DIM);
    const float4* rj = (const float4*)(ej + (size_t)i * DIM);
    float4 a0 = ri[t], a1 = ri[t + 64];
    float4 b0 = rj[t], b1 = rj[t + 64];

    float si  = a0.x*a0.x + a0.y*a0.y + a0.z*a0.z + a0.w*a0.w
              + a1.x*a1.x + a1.y*a1.y + a1.z*a1.z + a1.w*a1.w;
    float sj  = b0.x*b0.x + b0.y*b0.y + b0.z*b0.z + b0.w*b0.w
              + b1.x*b1.x + b1.y*b1.y + b1.z*b1.z + b1.w*b1.w;
    float dij = a0.x*b0.x + a0.y*b0.y + a0.z*b0.z + a0.w*b0.w
              + a1.x*b1.x + a1.y*b1.y + a1.z*b1.z + a1.w*b1.w;

    #pragma unroll
    for (int m = 1; m < 64; m <<= 1) {
        si  += __shfl_xor(si,  m);
        sj  += __shfl_xor(sj,  m);
        dij += __shfl_xor(dij, m);
    }
    float invi = 1.0f / fmaxf(sqrtf(si), 1e-12f);
    float invj = 1.0f / fmaxf(sqrtf(sj), 1e-12f);

    ushort4 o0, o1, p0, p1;
    o0.x = f2bf(a0.x*invi); o0.y = f2bf(a0.y*invi); o0.z = f2bf(a0.z*invi); o0.w = f2bf(a0.w*invi);
    o1.x = f2bf(a1.x*invi); o1.y = f2bf(a1.y*invi); o1.z = f2bf(a1.z*invi); o1.w = f2bf(a1.w*invi);
    p0.x = f2bf(b0.x*invj); p0.y = f2bf(b0.y*invj); p0.z = f2bf(b0.z*invj); p0.w = f2bf(b0.w*invj);
    p1.x = f2bf(b1.x*invj); p1.y = f2bf(b1.y*invj); p1.z = f2bf(b1.z*invj); p1.w = f2bf(b1.w*invj);

    ushort4* wi = (ushort4*)(reps + (size_t)i * DIM);
    ushort4* wj = (ushort4*)(reps + (size_t)(BATCH + i) * DIM);
    wi[t] = o0; wi[t + 64] = o1;
    wj[t] = p0; wj[t + 64] = p1;
    if (t == 0) pos[i] = dij * invi * invj;
}

// ---------------- Kernel 2a: full off-diagonal 256x256 cells ----------------
// 8 waves (2M x 4N), BK=64, 2 LDS slots of 4 half-tiles (128 KB), 4 phases per
// K-tile: {ds_read before barrier | burst-stage at tile start | lgkmcnt(0) |
// setprio MFMA x16 | barrier}, vmcnt(0) only at tile boundary (loads issued
// ~3 phases earlier -> cheap). No diag mask needed (rc < cc strictly).
__global__ __launch_bounds__(512, 2) void simfull_kernel(
    const unsigned short* __restrict__ reps, float* __restrict__ partials) {
    __shared__ unsigned short lds[8][8192];   // 8 half-tiles x 16 KB = 128 KB

    int bid = (blockIdx.x & 7) * (NFULL / 8) + (blockIdx.x >> 3);  // 496 = 8*62
    int rc = 0, b = bid;
    while (b >= NCH - 1 - rc) { b -= NCH - 1 - rc; ++rc; }
    const int cc = rc + 1 + b;                // rc < cc

    const int tid  = threadIdx.x;
    const int lane = tid & 63;
    const int wave = tid >> 6;
    const int wr = wave >> 2, wc = wave & 3;
    const int s = lane & 15, q = lane >> 4;
    const int rowBase = rc * TILE, colBase = cc * TILE;

    // staging: wave owns half-tile ht (0=A0,1=A1,2=B0,3=B1), 64-row half
    const int ht = wave >> 1;
    const int rows64 = (wave & 1) * 64;
    const int gRow0 = (ht < 2 ? rowBase + ht * 128 : colBase + (ht - 2) * 128) + rows64;
    const unsigned short* gsrc = reps + (size_t)gRow0 * DIM;
    const int lr  = lane >> 3;
    const int gsE = (lane & 7) ^ ((lane >> 4) & 3);
    const int gsO = (lane & 7) ^ (4 | ((lane >> 4) & 3));
    const int srcE = lr * DIM + gsE * 8;      // element offsets
    const int srcO = lr * DIM + gsO * 8;

    // ds_read swizzled byte offsets
    const int ko0 = ((q ^ (s >> 1)) << 4);
    const int ko1 = (((4 + q) ^ (s >> 1)) << 4);
    const int aBase = s * 128;
    const int bBase = (wc & 1) * 8192 + s * 128;

    f32x4 acc[8][4];
    #pragma unroll
    for (int m = 0; m < 8; ++m)
        #pragma unroll
        for (int n = 0; n < 4; ++n) acc[m][n] = (f32x4){0.f,0.f,0.f,0.f};

    // prologue: stage tile 0 -> slot 0
    {
        unsigned short* dst = &lds[ht][rows64 * 64];
        #pragma unroll
        for (int j = 0; j < 8; ++j)
            gload16(gsrc + (size_t)(j * 8) * DIM + ((j & 1) ? srcO : srcE), dst + j * 512);
    }
    asm volatile("s_waitcnt vmcnt(0)" ::: "memory");
    __builtin_amdgcn_s_barrier();

    #pragma unroll 2
    for (int t = 0; t < NT; ++t) {
        const int sl = t & 1;
        const char* Ah = (const char*)&lds[sl * 4 + wr][0];
        const char* Bh = (const char*)&lds[sl * 4 + 2 + (wc >> 1)][0];

        if (t < NT - 1) {   // burst-stage tile t+1 -> other slot
            unsigned short* dst = &lds[(sl ^ 1) * 4 + ht][rows64 * 64];
            const unsigned short* gk = gsrc + (t + 1) * BK;
            #pragma unroll
            for (int j = 0; j < 8; ++j)
                gload16(gk + (size_t)(j * 8) * DIM + ((j & 1) ? srcO : srcE), dst + j * 512);
        }

        bf16x8 af[4], bf[4];
        // ---- phase 0: (mh0, ks0) ----
        #pragma unroll
        for (int m = 0; m < 4; ++m) af[m] = *(const bf16x8*)(Ah + aBase + ko0 + m * 2048);
        #pragma unroll
        for (int n = 0; n < 4; ++n) bf[n] = *(const bf16x8*)(Bh + bBase + ko0 + n * 2048);
        __builtin_amdgcn_s_barrier();
        asm volatile("s_waitcnt lgkmcnt(0)" ::: "memory");
        __builtin_amdgcn_sched_barrier(0);
        __builtin_amdgcn_s_setprio(1);
        #pragma unroll
        for (int m = 0; m < 4; ++m)
            #pragma unroll
            for (int n = 0; n < 4; ++n)
                acc[m][n] = __builtin_amdgcn_mfma_f32_16x16x32_bf16(af[m], bf[n], acc[m][n], 0, 0, 0);
        __builtin_amdgcn_s_setprio(0);
        __builtin_amdgcn_s_barrier();
        // ---- phase 1: (mh1, ks0) ----
        #pragma unroll
        for (int m = 0; m < 4; ++m) af[m] = *(const bf16x8*)(Ah + aBase + ko0 + (4 + m) * 2048);
        __builtin_amdgcn_s_barrier();
        asm volatile("s_waitcnt lgkmcnt(0)" ::: "memory");
        __builtin_amdgcn_sched_barrier(0);
        __builtin_amdgcn_s_setprio(1);
        #pragma unroll
        for (int m = 0; m < 4; ++m)
            #pragma unroll
            for (int n = 0; n < 4; ++n)
                acc[4 + m][n] = __builtin_amdgcn_mfma_f32_16x16x32_bf16(af[m], bf[n], acc[4 + m][n], 0, 0, 0);
        __builtin_amdgcn_s_setprio(0);
        __builtin_amdgcn_s_barrier();
        // ---- phase 2: (mh0, ks1) ----
        #pragma unroll
        for (int m = 0; m < 4; ++m) af[m] = *(const bf16x8*)(Ah + aBase + ko1 + m * 2048);
        #pragma unroll
        for (int n = 0; n < 4; ++n) bf[n] = *(const bf16x8*)(Bh + bBase + ko1 + n * 2048);
        __builtin_amdgcn_s_barrier();
        asm volatile("s_waitcnt lgkmcnt(0)" ::: "memory");
        __builtin_amdgcn_sched_barrier(0);
        __builtin_amdgcn_s_setprio(1);
        #pragma unroll
        for (int m = 0; m < 4; ++m)
            #pragma unroll
            for (int n = 0; n < 4; ++n)
                acc[m][n] = __builtin_amdgcn_mfma_f32_16x16x32_bf16(af[m], bf[n], acc[m][n], 0, 0, 0);
        __builtin_amdgcn_s_setprio(0);
        __builtin_amdgcn_s_barrier();
        // ---- phase 3: (mh1, ks1) ----
        #pragma unroll
        for (int m = 0; m < 4; ++m) af[m] = *(const bf16x8*)(Ah + aBase + ko1 + (4 + m) * 2048);
        __builtin_amdgcn_s_barrier();
        asm volatile("s_waitcnt lgkmcnt(0)" ::: "memory");
        __builtin_amdgcn_sched_barrier(0);
        __builtin_amdgcn_s_setprio(1);
        #pragma unroll
        for (int m = 0; m < 4; ++m)
            #pragma unroll
            for (int n = 0; n < 4; ++n)
                acc[4 + m][n] = __builtin_amdgcn_mfma_f32_16x16x32_bf16(af[m], bf[n], acc[4 + m][n], 0, 0, 0);
        __builtin_amdgcn_s_setprio(0);
        asm volatile("s_waitcnt vmcnt(0)" ::: "memory");   // own burst, issued ~3 phases ago
        __builtin_amdgcn_s_barrier();                      // tile boundary
    }

    // ---- epilogue: exp(sim/T); row sums + col sums (no diag here) ----
    const float SCALE = 2.8853900817779268f;   // 2/ln2
    float* red = (float*)lds;                  // [4][256] rowsum | [2][256] colsum
    __syncthreads();
    float colacc[4] = {0.f,0.f,0.f,0.f};
    #pragma unroll
    for (int m = 0; m < 8; ++m) {
        float rs[4] = {0.f,0.f,0.f,0.f};
        #pragma unroll
        for (int n = 0; n < 4; ++n)
            #pragma unroll
            for (int j = 0; j < 4; ++j) {
                float e = exp2f(acc[m][n][j] * SCALE);
                rs[j] += e;
                colacc[n] += e;
            }
        #pragma unroll
        for (int j = 0; j < 4; ++j) {
            float v = rs[j];
            v += __shfl_xor(v, 1); v += __shfl_xor(v, 2);
            v += __shfl_xor(v, 4); v += __shfl_xor(v, 8);
            if (s == 0) red[wc * 256 + wr * 128 + m * 16 + q * 4 + j] = v;
        }
    }
    #pragma unroll
    for (int n = 0; n < 4; ++n) {
        float v = colacc[n];
        v += __shfl_xor(v, 16); v += __shfl_xor(v, 32);
        if (q == 0) red[1024 + wr * 256 + wc * 64 + n * 16 + s] = v;
    }
    __syncthreads();
    if (tid < 256) {
        partials[(size_t)cc * NROW + rowBase + tid] =
            red[tid] + red[256 + tid] + red[512 + tid] + red[768 + tid];
        partials[(size_t)rc * NROW + colBase + tid] =
            red[1024 + tid] + red[1280 + tid];
    }
}

// ---------------- Kernel 2b: diagonal 128x128 quarter-cells ----------------
// 96 blocks: d = bid/3 diag cell, sub 0/1 = pure-diag quarters, sub 2 = off-diag.
__global__ __launch_bounds__(256) void simdiag_kernel(
    const unsigned short* __restrict__ reps, float* __restrict__ partials) {
    __shared__ unsigned short As[QT * BK];
    __shared__ unsigned short Bs[QT * BK];
    __shared__ float red[2][QT];
    __shared__ float col[2][QT];

    const int bid = blockIdx.x;
    const int d = bid / 3, sub = bid % 3;
    const int rowBase = (2 * d + (sub == 1)) * QT;
    const int colBase = (2 * d + (sub >= 1)) * QT;
    const bool diag = (sub < 2);

    const int tid = threadIdx.x;
    const int lane = tid & 63;
    const int wave = tid >> 6;
    const int wr = wave >> 1, wc = wave & 1;
    const int s = lane & 15, q = lane >> 4;

    const unsigned short* gA = reps + (size_t)rowBase * DIM;
    const unsigned short* gB = reps + (size_t)colBase * DIM;
    const int lr = lane >> 3;
    const int gsE = (lane & 7) ^ ((lane >> 4) & 3);
    const int gsO = (lane & 7) ^ (4 | ((lane >> 4) & 3));
    const int ko0 = ((q ^ (s >> 1)) << 4);
    const int ko1 = (((4 + q) ^ (s >> 1)) << 4);

    f32x4 acc[4][4];
    #pragma unroll
    for (int m = 0; m < 4; ++m)
        #pragma unroll
        for (int n = 0; n < 4; ++n) acc[m][n] = (f32x4){0.f,0.f,0.f,0.f};

    for (int kb = 0; kb < DIM; kb += BK) {
        __syncthreads();
        #pragma unroll
        for (int i = 0; i < 4; ++i) {
            const int r0 = wave * 32 + i * 8;
            const int so = ((i & 1) ? gsO : gsE) * 8 + lr * DIM + kb;
            gload16(gA + (size_t)r0 * DIM + so, &As[r0 * 64]);
            gload16(gB + (size_t)r0 * DIM + so, &Bs[r0 * 64]);
        }
        __syncthreads();
        #pragma unroll
        for (int ks = 0; ks < 2; ++ks) {
            const int ko = ks ? ko1 : ko0;
            bf16x8 af[4], bf[4];
            #pragma unroll
            for (int m = 0; m < 4; ++m)
                af[m] = *(const bf16x8*)((const char*)As + (wr * 64 + m * 16 + s) * 128 + ko);
            #pragma unroll
            for (int n = 0; n < 4; ++n)
                bf[n] = *(const bf16x8*)((const char*)Bs + (wc * 64 + n * 16 + s) * 128 + ko);
            #pragma unroll
            for (int m = 0; m < 4; ++m)
                #pragma unroll
                for (int n = 0; n < 4; ++n)
                    acc[m][n] = __builtin_amdgcn_mfma_f32_16x16x32_bf16(af[m], bf[n], acc[m][n], 0, 0, 0);
        }
    }

    const float SCALE = 2.8853900817779268f;
    float colacc[4] = {0.f,0.f,0.f,0.f};
    #pragma unroll
    for (int m = 0; m < 4; ++m) {
        const int lrow0 = wr * 64 + m * 16 + (q << 2);
        float rs[4] = {0.f,0.f,0.f,0.f};
        #pragma unroll
        for (int n = 0; n < 4; ++n) {
            const int gcol = colBase + wc * 64 + n * 16 + s;
            #pragma unroll
            for (int j = 0; j < 4; ++j) {
                float e = exp2f(acc[m][n][j] * SCALE);
                if (diag && (rowBase + lrow0 + j == gcol)) e = 0.f;
                rs[j] += e;
                colacc[n] += e;
            }
        }
        #pragma unroll
        for (int j = 0; j < 4; ++j) {
            float v = rs[j];
            v += __shfl_xor(v, 1); v += __shfl_xor(v, 2);
            v += __shfl_xor(v, 4); v += __shfl_xor(v, 8);
            if (s == 0) red[wc][lrow0 + j] = v;
        }
    }
    #pragma unroll
    for (int n = 0; n < 4; ++n) {
        float v = colacc[n];
        v += __shfl_xor(v, 16); v += __shfl_xor(v, 32);
        if (q == 0) col[wr][wc * 64 + n * 16 + s] = v;
    }
    __syncthreads();
    if (tid < QT) {
        const int slotD = (sub == 2) ? 32 : d;
        partials[(size_t)slotD * NROW + rowBase + tid] = red[0][tid] + red[1][tid];
        if (sub == 2)
            partials[(size_t)32 * NROW + colBase + tid] = col[0][tid] + col[1][tid];
    }
}

// ---------------- Kernel 3a: per-row loss partial sums ----------------
__global__ __launch_bounds__(256) void rowloss_kernel(
    const float* __restrict__ partials, const float* __restrict__ pos,
    double* __restrict__ blocksum) {
    const int t = threadIdx.x;
    const int r = blockIdx.x * 256 + t;
    float denom = 0.f;
    #pragma unroll 11
    for (int c = 0; c < NSLOT; ++c)
        denom += partials[(size_t)c * NROW + r];
    double v = (double)(logf(denom) - 2.0f * pos[r & (BATCH - 1)]);
    __shared__ double redl[256];
    redl[t] = v;
    __syncthreads();
    for (int off = 128; off > 0; off >>= 1) {
        if (t < off) redl[t] += redl[t + off];
        __syncthreads();
    }
    if (t == 0) blocksum[blockIdx.x] = redl[0];
}

__global__ void final2_kernel(const double* __restrict__ blocksum,
                              float* __restrict__ out) {
    if (threadIdx.x == 0) {
        double ssum = 0.0;
        #pragma unroll
        for (int i = 0; i < NROW / 256; ++i) ssum += blocksum[i];
        out[0] = (float)(ssum / (double)NROW);
    }
}

extern "C" void kernel_launch(void* const* d_in, const int* in_sizes, int n_in,
                              void* d_out, int out_size, void* d_ws, size_t ws_size,
                              hipStream_t stream) {
    const float* ei = (const float*)d_in[0];
    const float* ej = (const float*)d_in[1];
    float* out = (float*)d_out;

    unsigned short* reps = (unsigned short*)d_ws;                       // 8 MB
    float* pos      = (float*)((char*)d_ws + (size_t)NROW * DIM * 2);   // 16 KB
    float* partials = pos + BATCH;                                      // 33*8192*4
    double* blocksum = (double*)(partials + (size_t)NSLOT * NROW);

    normalize_pos_kernel<<<BATCH / 4, 256, 0, stream>>>(ei, ej, reps, pos);
    simfull_kernel<<<NFULL, 512, 0, stream>>>(reps, partials);
    simdiag_kernel<<<NQ, 256, 0, stream>>>(reps, partials);
    rowloss_kernel<<<NROW / 256, 256, 0, stream>>>(partials, pos, blocksum);
    final2_kernel<<<1, 64, 0, stream>>>(blocksum, out);
}